// Round 1
// baseline (453.060 us; speedup 1.0000x reference)
//
#include <hip/hip_runtime.h>

#define U 4096
#define S 8192
#define D 32
#define NUM_REGIONS 128
#define GA 0.1f

#define TU 32      // users per block
#define TI 512     // items per block (2 per thread)
#define THREADS 256

// ---------------- fused region loss: one block per region ----------------
// Eliminates the 135K-global-atomic storm (cross-XCD cacheline ping-pong).
// Each block: stage region_index in LDS, compute sum[D]+count for its region,
// then the LOO deviation loss for its users. 128 atomics total.

__global__ __launch_bounds__(256) void region_kernel(
    const float* __restrict__ user_emb,
    const int* __restrict__ region_index,
    float* __restrict__ rl_accum) {
    __shared__ int   ridx[U];        // 16 KB
    __shared__ float part[8][D];     // 1 KB partial sums
    __shared__ float partc[8];
    __shared__ float redsum[D];
    __shared__ float redcnt;

    // cooperative load of region_index (16 KB, L2-resident)
    for (int i = threadIdx.x; i < U / 4; i += 256)
        ((int4*)ridx)[i] = ((const int4*)region_index)[i];
    __syncthreads();

    const int r = blockIdx.x;                 // region id
    const int d = threadIdx.x & (D - 1);      // dim 0..31
    const int w = threadIdx.x >> 5;           // user stripe 0..7

    // pass 1: sum + count for region r
    float psum = 0.0f;
    float pcnt = 0.0f;
    for (int u = w; u < U; u += 8) {
        if (ridx[u] == r) {
            psum += user_emb[u * D + d];
            pcnt += 1.0f;
        }
    }
    part[w][d] = psum;
    if (d == 0) partc[w] = pcnt;
    __syncthreads();
    if (w == 0) {
        float s = 0.0f;
        #pragma unroll
        for (int i = 0; i < 8; i++) s += part[i][d];
        redsum[d] = s;
    }
    if (threadIdx.x == 0) {
        float c = 0.0f;
        #pragma unroll
        for (int i = 0; i < 8; i++) c += partc[i];
        redcnt = c;
    }
    __syncthreads();

    // pass 2: leave-one-out deviation for users of region r
    const float cnt = redcnt;
    float acc = 0.0f;
    if (cnt > 1.0f) {
        const float inv = 1.0f / (cnt - 1.0f);   // cnt>=2 -> max(cnt-1,1)=cnt-1
        const float sd = redsum[d];
        for (int u = w; u < U; u += 8) {
            if (ridx[u] == r) {
                float e = user_emb[u * D + d];
                acc += fabsf(e - (sd - e) * inv);
            }
        }
    }

    // block reduce + one atomic per block
    #pragma unroll
    for (int off = 32; off > 0; off >>= 1) acc += __shfl_down(acc, off, 64);
    __shared__ float wp[4];
    int lane = threadIdx.x & 63, wid = threadIdx.x >> 6;
    if (lane == 0) wp[wid] = acc;
    __syncthreads();
    if (threadIdx.x == 0)
        atomicAdd(rl_accum, wp[0] + wp[1] + wp[2] + wp[3]);
}

// ---------------- main masked-MSE kernel ----------------

// pin a float4 in VGPRs so the compiler cannot rematerialize its load
#define PIN4(v) asm volatile("" : "+v"(v.x), "+v"(v.y), "+v"(v.z), "+v"(v.w))

__global__ __launch_bounds__(THREADS, 2) void mse_kernel(
    const float* __restrict__ user_emb,
    const float* __restrict__ item_emb,
    const int* __restrict__ train_mask,
    const float* __restrict__ true_qos,
    const float* __restrict__ us_lossweight,
    float* __restrict__ loss_accum) {
    __shared__ float uemb[TU][D];  // 4 KB user tile

    const int ub = blockIdx.x * TU;
    const int sb = blockIdx.y * TI;

    // cooperative load of user tile: TU*D = 1024 floats = 256 float4
    {
        const float4* src = (const float4*)(user_emb + (size_t)ub * D);
        ((float4*)&uemb[0][0])[threadIdx.x] = src[threadIdx.x];
    }

    const int s0 = sb + 2 * threadIdx.x;  // this thread's 2 items

    // item rows into registers (L2-resident; MUST stay register-held —
    // at 56 VGPR the old build re-loaded 256B/thread/iter => ~4GB L2 traffic)
    float4 ir0[8], ir1[8];
    {
        const float4* ip0 = (const float4*)(item_emb + (size_t)s0 * D);
        const float4* ip1 = (const float4*)(item_emb + (size_t)(s0 + 1) * D);
        #pragma unroll
        for (int k = 0; k < 8; k++) { ir0[k] = ip0[k]; ir1[k] = ip1[k]; }
        #pragma unroll
        for (int k = 0; k < 8; k++) { PIN4(ir0[k]); PIN4(ir1[k]); }
    }
    __syncthreads();

    // software-pipelined streaming loads: prefetch next user row
    const size_t base0 = (size_t)ub * S + s0;
    int2   m_n = *(const int2*)(train_mask + base0);
    float2 q_n = *(const float2*)(true_qos + base0);
    float2 w_n = *(const float2*)(us_lossweight + base0);

    float acc = 0.0f;
    #pragma unroll 1
    for (int uu = 0; uu < TU; uu++) {
        int2   m = m_n;
        float2 q = q_n;
        float2 w = w_n;
        if (uu + 1 < TU) {
            const size_t nb = base0 + (size_t)(uu + 1) * S;
            m_n = *(const int2*)(train_mask + nb);
            q_n = *(const float2*)(true_qos + nb);
            w_n = *(const float2*)(us_lossweight + nb);
        }

        float d0 = 0.0f, d1 = 0.0f;
        const float4* ur = (const float4*)&uemb[uu][0];  // broadcast LDS reads
        #pragma unroll
        for (int k = 0; k < 8; k++) {
            float4 uv = ur[k];
            d0 += uv.x * ir0[k].x + uv.y * ir0[k].y + uv.z * ir0[k].z + uv.w * ir0[k].w;
            d1 += uv.x * ir1[k].x + uv.y * ir1[k].y + uv.z * ir1[k].z + uv.w * ir1[k].w;
        }
        float p0 = d0 * (float)m.x;
        float p1 = d1 * (float)m.y;
        float e0 = p0 - q.x;
        float e1 = p1 - q.y;
        acc += w.x * e0 * e0 + w.y * e1 * e1;
    }

    // wave64 reduce + one atomic per block
    #pragma unroll
    for (int off = 32; off > 0; off >>= 1) acc += __shfl_down(acc, off, 64);
    __shared__ float wp[THREADS / 64];
    int lane = threadIdx.x & 63, wid = threadIdx.x >> 6;
    if (lane == 0) wp[wid] = acc;
    __syncthreads();
    if (threadIdx.x == 0) {
        float t = 0.0f;
        #pragma unroll
        for (int i = 0; i < THREADS / 64; i++) t += wp[i];
        atomicAdd(loss_accum, t);
    }
}

__global__ void finalize_kernel(const float* __restrict__ loss_acc,
                                const float* __restrict__ rl_acc,
                                float* __restrict__ out) {
    out[0] = loss_acc[0] + GA * rl_acc[0];
}

extern "C" void kernel_launch(void* const* d_in, const int* in_sizes, int n_in,
                              void* d_out, int out_size, void* d_ws, size_t ws_size,
                              hipStream_t stream) {
    const float* user_emb      = (const float*)d_in[0];
    const float* item_emb      = (const float*)d_in[1];
    const int*   train_mask    = (const int*)d_in[2];
    const float* true_qos      = (const float*)d_in[3];
    const float* us_lossweight = (const float*)d_in[4];
    const int*   region_index  = (const int*)d_in[5];
    float* out = (float*)d_out;

    float* ws       = (float*)d_ws;
    float* loss_acc = ws;          // 1
    float* rl_acc   = ws + 1;      // 1
    hipMemsetAsync(d_ws, 0, 2 * sizeof(float), stream);

    region_kernel<<<NUM_REGIONS, 256, 0, stream>>>(user_emb, region_index, rl_acc);

    dim3 grid(U / TU, S / TI);
    mse_kernel<<<grid, THREADS, 0, stream>>>(
        user_emb, item_emb, train_mask, true_qos, us_lossweight, loss_acc);

    finalize_kernel<<<1, 1, 0, stream>>>(loss_acc, rl_acc, out);
}

// Round 3
// 376.929 us; speedup vs baseline: 1.2020x; 1.2020x over previous
//
#include <hip/hip_runtime.h>

#define U 4096
#define S 8192
#define D 32
#define NUM_REGIONS 128
#define GA 0.1f

#define TU 32      // users per block
#define TI 512     // items per block (2 per thread)
#define THREADS 256
#define LCAP 256   // max users per region (expected ~32)

// ---------------- region loss: one block per region, list-based ----------------
// Parallel scan across all 256 threads builds a compact user list (~32 entries),
// then sum/LOO loops run over the list only. 128 global atomics total.

__global__ __launch_bounds__(256) void region_kernel(
    const float* __restrict__ user_emb,
    const int* __restrict__ region_index,
    float* __restrict__ rl_accum) {
    __shared__ int   ridx[U];        // 16 KB
    __shared__ int   ulist[LCAP];
    __shared__ int   ucnt;
    __shared__ float part[8][D];     // 1 KB partial sums
    __shared__ float redsum[D];

    if (threadIdx.x == 0) ucnt = 0;

    // cooperative load of region_index (16 KB): 4 int4 per thread
    #pragma unroll
    for (int i = 0; i < U / 4 / 256; i++)
        ((int4*)ridx)[threadIdx.x + i * 256] =
            ((const int4*)region_index)[threadIdx.x + i * 256];
    __syncthreads();

    const int r = blockIdx.x;

    // parallel scan: all 256 threads stride the user list (16 iters)
    for (int u = threadIdx.x; u < U; u += 256) {
        if (ridx[u] == r) {
            int p = atomicAdd(&ucnt, 1);
            if (p < LCAP) ulist[p] = u;
        }
    }
    __syncthreads();

    const int n = min(ucnt, LCAP);
    const int d = threadIdx.x & (D - 1);      // dim 0..31
    const int w = threadIdx.x >> 5;           // list stripe 0..7

    // pass 1: region sum over the compact list (~4 iters per stripe)
    float psum = 0.0f;
    for (int i = w; i < n; i += 8)
        psum += user_emb[ulist[i] * D + d];
    part[w][d] = psum;
    __syncthreads();
    if (w == 0) {
        float s = 0.0f;
        #pragma unroll
        for (int i = 0; i < 8; i++) s += part[i][d];
        redsum[d] = s;
    }
    __syncthreads();

    // pass 2: leave-one-out deviation over the list
    float acc = 0.0f;
    if (n > 1) {
        const float inv = 1.0f / (float)(n - 1);
        const float sd = redsum[d];
        for (int i = w; i < n; i += 8) {
            float e = user_emb[ulist[i] * D + d];
            acc += fabsf(e - (sd - e) * inv);
        }
    }

    // block reduce + one atomic per block
    #pragma unroll
    for (int off = 32; off > 0; off >>= 1) acc += __shfl_down(acc, off, 64);
    __shared__ float wp[4];
    int lane = threadIdx.x & 63, wid = threadIdx.x >> 6;
    if (lane == 0) wp[wid] = acc;
    __syncthreads();
    if (threadIdx.x == 0)
        atomicAdd(rl_accum, wp[0] + wp[1] + wp[2] + wp[3]);
}

// ---------------- main masked-MSE kernel ----------------

// pin a float4 in VGPRs so the compiler cannot rematerialize its load
#define PIN4(v) asm volatile("" : "+v"(v.x), "+v"(v.y), "+v"(v.z), "+v"(v.w))

// waves_per_eu(4,4): 128-VGPR allocator budget so the 64 item-row floats
// stay register-resident. Default build targeted 8 waves/EU (<=64 VGPR)
// and rematerialized the item loads every uu-iteration => ~4.3 GB of L2
// traffic at ~30 TB/s = the real 141us bottleneck (HBM was only 18%).
// Measured occupancy was already ~40-48%, so 4 waves/EU costs nothing.
__global__ __attribute__((amdgpu_waves_per_eu(4, 4)))
void mse_kernel(
    const float* __restrict__ user_emb,
    const float* __restrict__ item_emb,
    const int* __restrict__ train_mask,
    const float* __restrict__ true_qos,
    const float* __restrict__ us_lossweight,
    float* __restrict__ loss_accum) {
    __shared__ float uemb[TU][D];  // 4 KB user tile

    const int ub = blockIdx.x * TU;
    const int sb = blockIdx.y * TI;

    // cooperative load of user tile: TU*D = 1024 floats = 256 float4
    {
        const float4* src = (const float4*)(user_emb + (size_t)ub * D);
        ((float4*)&uemb[0][0])[threadIdx.x] = src[threadIdx.x];
    }

    const int s0 = sb + 2 * threadIdx.x;  // this thread's 2 items

    // item rows into registers — must stay register-held (64 VGPRs).
    float4 ir0[8], ir1[8];
    {
        const float4* ip0 = (const float4*)(item_emb + (size_t)s0 * D);
        const float4* ip1 = (const float4*)(item_emb + (size_t)(s0 + 1) * D);
        #pragma unroll
        for (int k = 0; k < 8; k++) { ir0[k] = ip0[k]; ir1[k] = ip1[k]; }
        #pragma unroll
        for (int k = 0; k < 8; k++) { PIN4(ir0[k]); PIN4(ir1[k]); }
    }
    __syncthreads();

    // software-pipelined streaming loads: prefetch next user row
    const size_t base0 = (size_t)ub * S + s0;
    int2   m_n = *(const int2*)(train_mask + base0);
    float2 q_n = *(const float2*)(true_qos + base0);
    float2 w_n = *(const float2*)(us_lossweight + base0);

    float acc = 0.0f;
    #pragma unroll 1
    for (int uu = 0; uu < TU; uu++) {
        int2   m = m_n;
        float2 q = q_n;
        float2 w = w_n;
        if (uu + 1 < TU) {
            const size_t nb = base0 + (size_t)(uu + 1) * S;
            m_n = *(const int2*)(train_mask + nb);
            q_n = *(const float2*)(true_qos + nb);
            w_n = *(const float2*)(us_lossweight + nb);
        }

        float d0 = 0.0f, d1 = 0.0f;
        const float4* ur = (const float4*)&uemb[uu][0];  // broadcast LDS reads
        #pragma unroll
        for (int k = 0; k < 8; k++) {
            float4 uv = ur[k];
            d0 += uv.x * ir0[k].x + uv.y * ir0[k].y + uv.z * ir0[k].z + uv.w * ir0[k].w;
            d1 += uv.x * ir1[k].x + uv.y * ir1[k].y + uv.z * ir1[k].z + uv.w * ir1[k].w;
        }
        float p0 = d0 * (float)m.x;
        float p1 = d1 * (float)m.y;
        float e0 = p0 - q.x;
        float e1 = p1 - q.y;
        acc += w.x * e0 * e0 + w.y * e1 * e1;
    }

    // wave64 reduce + one atomic per block
    #pragma unroll
    for (int off = 32; off > 0; off >>= 1) acc += __shfl_down(acc, off, 64);
    __shared__ float wp[THREADS / 64];
    int lane = threadIdx.x & 63, wid = threadIdx.x >> 6;
    if (lane == 0) wp[wid] = acc;
    __syncthreads();
    if (threadIdx.x == 0) {
        float t = 0.0f;
        #pragma unroll
        for (int i = 0; i < THREADS / 64; i++) t += wp[i];
        atomicAdd(loss_accum, t);
    }
}

__global__ void finalize_kernel(const float* __restrict__ loss_acc,
                                const float* __restrict__ rl_acc,
                                float* __restrict__ out) {
    out[0] = loss_acc[0] + GA * rl_acc[0];
}

extern "C" void kernel_launch(void* const* d_in, const int* in_sizes, int n_in,
                              void* d_out, int out_size, void* d_ws, size_t ws_size,
                              hipStream_t stream) {
    const float* user_emb      = (const float*)d_in[0];
    const float* item_emb      = (const float*)d_in[1];
    const int*   train_mask    = (const int*)d_in[2];
    const float* true_qos      = (const float*)d_in[3];
    const float* us_lossweight = (const float*)d_in[4];
    const int*   region_index  = (const int*)d_in[5];
    float* out = (float*)d_out;

    float* ws       = (float*)d_ws;
    float* loss_acc = ws;          // 1
    float* rl_acc   = ws + 1;      // 1
    hipMemsetAsync(d_ws, 0, 2 * sizeof(float), stream);

    region_kernel<<<NUM_REGIONS, 256, 0, stream>>>(user_emb, region_index, rl_acc);

    dim3 grid(U / TU, S / TI);
    mse_kernel<<<grid, THREADS, 0, stream>>>(
        user_emb, item_emb, train_mask, true_qos, us_lossweight, loss_acc);

    finalize_kernel<<<1, 1, 0, stream>>>(loss_acc, rl_acc, out);
}